// Round 8
// baseline (208.675 us; speedup 1.0000x reference)
//
#include <hip/hip_runtime.h>
#include <math.h>

static constexpr int B_  = 2;
static constexpr int S_  = 2048;
static constexpr int H_  = 16;
static constexpr int DH_ = 64;
// Q pre-scale = 1/sqrt(192) * log2(e) so flash softmax uses raw v_exp_f32 (exp2)
static constexpr float QSCALE2_ = 0.104117589f;
static constexpr float C8L2_    = 11.5415603f;     // 8 * log2(e) (static-max shift)

typedef __attribute__((ext_vector_type(8))) short short8;   // 8 x bf16
typedef __attribute__((ext_vector_type(4))) float floatx4;  // MFMA acc

__device__ __forceinline__ float bf2f(unsigned short u) {
    union { unsigned int i; float f; } c; c.i = ((unsigned int)u) << 16; return c.f;
}
__device__ __forceinline__ unsigned short f2bf(float f) {
    union { float f; unsigned int i; } c; c.f = f;
    unsigned int x = c.i;
    unsigned int r = (x + 0x7fffu + ((x >> 16) & 1u)) >> 16;
    if ((x & 0x7f800000u) == 0x7f800000u) r = x >> 16;   // inf/nan passthrough
    return (unsigned short)r;
}
__device__ __forceinline__ void load_lds16(const unsigned short* g, unsigned short* l) {
    __builtin_amdgcn_global_load_lds(
        (const __attribute__((address_space(1))) unsigned int*)g,
        (__attribute__((address_space(3))) unsigned int*)l, 16, 0, 0);
}

// ---------------------------------------------------------------------------
// prep: one launch doing cvt_x (blocks 0..4095), w_qkv transpose
// (4096..7167), w_out transpose (7168..8191).
// ---------------------------------------------------------------------------
__global__ __launch_bounds__(256) void prep(
    const float* __restrict__ x,     unsigned short* __restrict__ xb,
    const float* __restrict__ w_qkv, unsigned short* __restrict__ wqkvT,
    const float* __restrict__ w_out, unsigned short* __restrict__ woutT)
{
    __shared__ float t[32][33];
    const int bid = blockIdx.x;
    if (bid < 4096) {
        const int i = bid * 256 + threadIdx.x;
        const float4 v = reinterpret_cast<const float4*>(x)[i];
        ushort4 r;
        r.x = f2bf(v.x); r.y = f2bf(v.y); r.z = f2bf(v.z); r.w = f2bf(v.w);
        reinterpret_cast<ushort4*>(xb)[i] = r;
        return;
    }
    const float* in; unsigned short* out; int NN, bx, by;
    if (bid < 7168) {
        in = w_qkv; out = wqkvT; NN = 3072;
        const int b2 = bid - 4096; bx = b2 % 96; by = b2 / 96;
    } else {
        in = w_out; out = woutT; NN = 1024;
        const int b2 = bid - 7168; bx = b2 & 31; by = b2 >> 5;
    }
    const int n0 = bx * 32;
    const int k0 = by * 32;
    const int tn = threadIdx.x & 31, tk = threadIdx.x >> 5;   // tk 0..7
    #pragma unroll
    for (int i = 0; i < 4; ++i)
        t[tk + 8 * i][tn] = in[(size_t)(k0 + tk + 8 * i) * NN + n0 + tn];
    __syncthreads();
    #pragma unroll
    for (int i = 0; i < 4; ++i)
        out[(size_t)(n0 + tk + 8 * i) * 1024 + k0 + tn] = f2bf(t[tn][tk + 8 * i]);
}

// ---------------------------------------------------------------------------
// MFMA GEMM: C(128x128) = A(Mx1024 bf16) * BT(3072x1024 bf16)^T.
// bias + RoPE epilogue:
//   Q -> bf16 (B,H,S,DH), scaled by 1/sqrt(192)*log2e
//   K -> bf16 (B,H,S,DH)
//   V -> bf16 (B,H,DH,S)  TRANSPOSED (so flash stages V^T with vector ops)
// ---------------------------------------------------------------------------
__global__ __launch_bounds__(256) void gemm_qkv(
    const unsigned short* __restrict__ A, const unsigned short* __restrict__ BT,
    const float* __restrict__ bias,
    unsigned short* __restrict__ O0, unsigned short* __restrict__ O1,
    unsigned short* __restrict__ O2)
{
    __shared__ unsigned short As[128 * 32];
    __shared__ unsigned short Bs[128 * 32];

    const int tid  = threadIdx.x;
    const int wave = tid >> 6;
    const int lane = tid & 63;
    const int quad = lane >> 4;
    const int lm   = lane & 15;
    const int wm = (wave >> 1) * 64;
    const int wn = (wave & 1) * 64;
    const int n0 = blockIdx.x * 128;
    const int m0 = blockIdx.y * 128;

    floatx4 acc[4][4] = {};

    const int sr = lane >> 2;
    const int sc = lane & 3;

    for (int k0 = 0; k0 < 1024; k0 += 32) {
        #pragma unroll
        for (int rep = 0; rep < 2; ++rep) {
            const int r = wave * 32 + rep * 16;
            load_lds16(A  + (size_t)(m0 + r + sr) * 1024 + k0 + sc * 8, &As[r * 32]);
            load_lds16(BT + (size_t)(n0 + r + sr) * 1024 + k0 + sc * 8, &Bs[r * 32]);
        }
        __syncthreads();
        short8 af[4], bf[4];
        #pragma unroll
        for (int i = 0; i < 4; ++i) {
            af[i] = *reinterpret_cast<const short8*>(&As[(wm + i * 16 + lm) * 32 + quad * 8]);
            bf[i] = *reinterpret_cast<const short8*>(&Bs[(wn + i * 16 + lm) * 32 + quad * 8]);
        }
        #pragma unroll
        for (int mi = 0; mi < 4; ++mi)
            #pragma unroll
            for (int ni = 0; ni < 4; ++ni)
                acc[mi][ni] = __builtin_amdgcn_mfma_f32_16x16x32_bf16(
                    af[mi], bf[ni], acc[mi][ni], 0, 0, 0);
        __syncthreads();
    }

    const int nbase = n0 + wn;
    const int h   = nbase / 192;
    const int sec = (nbase - h * 192) >> 6;      // 0=q 1=k 2=v
    float bia[4];
    #pragma unroll
    for (int ni = 0; ni < 4; ++ni) bia[ni] = bias[nbase + ni * 16 + lm];
    unsigned short* Out = (sec == 0) ? O0 : ((sec == 1) ? O1 : O2);

    if (sec == 2) {
        // V^T store: (B,H,DH,S); lane holds 4 consecutive s -> ushort4
        #pragma unroll
        for (int mi = 0; mi < 4; ++mi) {
            const int m  = m0 + wm + mi * 16 + quad * 4;
            const int bb = m >> 11;
            const int s  = m & (S_ - 1);
            const size_t rowb = (size_t)(bb * H_ + h) * DH_;
            #pragma unroll
            for (int ni = 0; ni < 4; ++ni) {
                const int d = ni * 16 + lm;
                ushort4 w;
                w.x = f2bf(acc[mi][ni][0] + bia[ni]);
                w.y = f2bf(acc[mi][ni][1] + bia[ni]);
                w.z = f2bf(acc[mi][ni][2] + bia[ni]);
                w.w = f2bf(acc[mi][ni][3] + bia[ni]);
                *reinterpret_cast<ushort4*>(&Out[(rowb + d) * S_ + s]) = w;
            }
        }
    } else {
        const float qscale = (sec == 0) ? QSCALE2_ : 1.0f;
        const float nlf = -13.287712379549449f / 32.0f;   // -log2(1e4)/32
        const float invf0 = exp2f((float)lm * nlf);
        const float invf1 = exp2f((float)(lm + 16) * nlf);
        #pragma unroll
        for (int mi = 0; mi < 4; ++mi) {
            #pragma unroll
            for (int r = 0; r < 4; ++r) {
                const int m  = m0 + wm + mi * 16 + quad * 4 + r;
                const int bb = m >> 11;
                const int s  = m & (S_ - 1);
                const size_t obase = ((size_t)(bb * H_ + h) * S_ + s) * DH_;
                const float a0 = (float)s * invf0, a1 = (float)s * invf1;
                const float sn0 = __sinf(a0), cs0 = __cosf(a0);
                const float sn1 = __sinf(a1), cs1 = __cosf(a1);
                #pragma unroll
                for (int ni = 0; ni < 4; ++ni) {
                    const int d = ni * 16 + lm;
                    const float v = acc[mi][ni][r]     + bia[ni];
                    const float p = acc[mi][ni ^ 2][r] + bia[ni ^ 2];  // d^32 partner
                    const float cs = (ni & 1) ? cs1 : cs0;
                    const float sn = (ni & 1) ? sn1 : sn0;
                    float res = (d < 32) ? (v * cs - p * sn) : (v * cs + p * sn);
                    Out[obase + d] = f2bf(res * qscale);
                }
            }
        }
    }
}

// ---------------------------------------------------------------------------
// Output projection: C(64x128) tiles = A(4096x1024 bf16) * BT(1024x1024)^T.
// BM=64 -> grid 8x64 = 512 blocks = 2 blocks/CU (cross-block barrier overlap).
// ---------------------------------------------------------------------------
__global__ __launch_bounds__(256) void gemm_out(
    const unsigned short* __restrict__ A, const unsigned short* __restrict__ BT,
    const float* __restrict__ bias, float* __restrict__ Of)
{
    __shared__ unsigned short As[64 * 32];
    __shared__ unsigned short Bs[128 * 32];

    const int tid  = threadIdx.x;
    const int wave = tid >> 6;
    const int lane = tid & 63;
    const int quad = lane >> 4;
    const int lm   = lane & 15;
    const int wm = (wave >> 1) * 32;
    const int wn = (wave & 1) * 64;
    const int n0 = blockIdx.x * 128;
    const int m0 = blockIdx.y * 64;

    floatx4 acc[2][4] = {};

    const int sr = lane >> 2;
    const int sc = lane & 3;

    for (int k0 = 0; k0 < 1024; k0 += 32) {
        load_lds16(A + (size_t)(m0 + wave * 16 + sr) * 1024 + k0 + sc * 8,
                   &As[wave * 16 * 32]);
        #pragma unroll
        for (int rep = 0; rep < 2; ++rep) {
            const int r = wave * 32 + rep * 16;
            load_lds16(BT + (size_t)(n0 + r + sr) * 1024 + k0 + sc * 8, &Bs[r * 32]);
        }
        __syncthreads();
        short8 af[2], bf[4];
        #pragma unroll
        for (int i = 0; i < 2; ++i)
            af[i] = *reinterpret_cast<const short8*>(&As[(wm + i * 16 + lm) * 32 + quad * 8]);
        #pragma unroll
        for (int i = 0; i < 4; ++i)
            bf[i] = *reinterpret_cast<const short8*>(&Bs[(wn + i * 16 + lm) * 32 + quad * 8]);
        #pragma unroll
        for (int mi = 0; mi < 2; ++mi)
            #pragma unroll
            for (int ni = 0; ni < 4; ++ni)
                acc[mi][ni] = __builtin_amdgcn_mfma_f32_16x16x32_bf16(
                    af[mi], bf[ni], acc[mi][ni], 0, 0, 0);
        __syncthreads();
    }

    #pragma unroll
    for (int ni = 0; ni < 4; ++ni) {
        const int gn = n0 + wn + ni * 16 + lm;
        const float b = bias[gn];
        #pragma unroll
        for (int mi = 0; mi < 2; ++mi) {
            const int gm = m0 + wm + mi * 16 + quad * 4;
            #pragma unroll
            for (int r = 0; r < 4; ++r)
                Of[(size_t)(gm + r) * 1024 + gn] = acc[mi][ni][r] + b;
        }
    }
}

// ---------------------------------------------------------------------------
// MFMA flash attention v10: parity k-split — ALL waves active EVERY iter.
//  - block = ONE 64-q tile, 8 waves = 4 q-strips x 2 kt-parities.
//    waves 0-3 compute even kt, waves 4-7 odd kt, concurrently from
//    parity-indexed LDS tiles (Ks[2], Vs[2]); 2 barriers/iter = 1/kt-tile.
//  - per-wave iterations = ceil((qt+1)/2): perfect within-block balance
//    (fixes v9's lo-idle: 67% -> ~100% active waves).
//  - grid 1024 (32 bh x 32 qt, heavy-qt first), 52.2 KB LDS -> 3 blocks/CU
//    = 24 ACTIVE waves/CU (v9: 16 resident, 10.8 active).
//  - end-of-block parity merge via Ps buffer (exactly 17408 B, stride-17
//    floats -> conflict-free); even-group finishes epilogue.
//  - swapped QK^T, exp2 softmax, cvt_pk P-store, reg prefetch 1 pair ahead.
// ---------------------------------------------------------------------------
static constexpr int KST = 68;   // Ks/Vs row stride (ushorts)
static constexpr int PST = 68;   // Ps row stride

__global__ __launch_bounds__(512, 6) void flash_mfma(
    const unsigned short* __restrict__ Q, const unsigned short* __restrict__ K,
    const unsigned short* __restrict__ VT, unsigned short* __restrict__ Ao)
{
    __shared__ unsigned short Ks[2][64 * KST];     // [parity][key][d]
    __shared__ unsigned short Vs[2][64 * KST];     // [parity][d][key]
    __shared__ unsigned short Ps[8][16 * PST];     // per-wave P / merge buffer

    const int bid = blockIdx.x;          // 0..1023
    const int qt  = 31 - (bid >> 5);     // heavy q-tiles first
    const int bh  = bid & 31;
    const int h   = bh & 15;
    const int b   = bh >> 4;
    const int tid  = threadIdx.x;        // 0..511
    const int wave = tid >> 6;           // 0..7
    const int lane = tid & 63;
    const int quad = lane >> 4;
    const int lm   = lane & 15;
    const int grp  = wave >> 2;          // kt parity (0=even, 1=odd)
    const int wq   = wave & 3;           // q-strip
    const int niter = (qt + 2) >> 1;     // ceil((qt+1)/2)
    const int srow = tid >> 3;           // staging row 0..63
    const int sc8  = tid & 7;            // staging chunk 0..7

    const unsigned short* Kg  = K  + (size_t)bh * S_ * DH_;
    const unsigned short* VTg = VT + (size_t)bh * DH_ * S_;

    // slope * MAX_BIAS * log2e
    const float slope2 = exp2f(-0.5f * (float)(h + 1)) * (8.0f * 1.44269504f);
    const float d64  = 64.0f * slope2;
    const float d128 = 2.0f * d64;

    int   koff[4];
    float alb[4];
    #pragma unroll
    for (int t = 0; t < 4; ++t) {
        koff[t] = t * 16 + quad * 4 - wq * 16 - lm;
        alb[t]  = (float)koff[t] * slope2 - C8L2_;
    }

    unsigned short* Pw = &Ps[wave][0];

    // Q B-frags: col q = lm of this wave's 16-q strip
    const unsigned short* Qrow =
        Q + ((size_t)bh * S_ + (size_t)(qt * 64 + wq * 16 + lm)) * DH_;
    const short8 aq0 = *reinterpret_cast<const short8*>(Qrow + quad * 8);
    const short8 aq1 = *reinterpret_cast<const short8*>(Qrow + 32 + quad * 8);

    float crk[4];
    #pragma unroll
    for (int r = 0; r < 4; ++r)
        crk[r] = (float)r * slope2 - (float)qt * d64 + (float)grp * d64;

    float l_one = 0.0f;
    floatx4 acc_o[4] = {};

    // ---- prologue: pair {0,1} -> regs -> LDS; pair {2,3} -> regs ----
    short8 ke, ko, ve, vo;
    ke = *reinterpret_cast<const short8*>(Kg + (size_t)srow * DH_ + sc8 * 8);
    ko = *reinterpret_cast<const short8*>(Kg + (size_t)(64 + srow) * DH_ + sc8 * 8);
    ve = *reinterpret_cast<const short8*>(VTg + (size_t)srow * S_ + sc8 * 8);
    vo = *reinterpret_cast<const short8*>(VTg + (size_t)srow * S_ + 64 + sc8 * 8);
    *reinterpret_cast<short8*>(&Ks[0][srow * KST + sc8 * 8]) = ke;
    *reinterpret_cast<short8*>(&Ks[1][srow * KST + sc8 * 8]) = ko;
    *reinterpret_cast<short8*>(&Vs[0][srow * KST + sc8 * 8]) = ve;
    *reinterpret_cast<short8*>(&Vs[1][srow * KST + sc8 * 8]) = vo;
    if (niter > 1) {
        ke = *reinterpret_cast<const short8*>(Kg + (size_t)(128 + srow) * DH_ + sc8 * 8);
        ko = *reinterpret_cast<const short8*>(Kg + (size_t)(192 + srow) * DH_ + sc8 * 8);
        ve = *reinterpret_cast<const short8*>(VTg + (size_t)srow * S_ + 128 + sc8 * 8);
        vo = *reinterpret_cast<const short8*>(VTg + (size_t)srow * S_ + 192 + sc8 * 8);
    }
    __syncthreads();

    for (int i = 0; i < niter; ++i) {
        const int ktg = 2 * i + grp;     // this wave-group's kt tile

        if (ktg <= qt) {
            // ---- S^T = K Q^T (swapped operands) ----
            floatx4 sacc[4] = {};
            __builtin_amdgcn_s_setprio(1);
            #pragma unroll
            for (int t = 0; t < 4; ++t) {
                const short8 k0 = *reinterpret_cast<const short8*>(&Ks[grp][(t * 16 + lm) * KST + quad * 8]);
                const short8 k1 = *reinterpret_cast<const short8*>(&Ks[grp][(t * 16 + lm) * KST + 32 + quad * 8]);
                sacc[t] = __builtin_amdgcn_mfma_f32_16x16x32_bf16(k0, aq0, sacc[t], 0, 0, 0);
                sacc[t] = __builtin_amdgcn_mfma_f32_16x16x32_bf16(k1, aq1, sacc[t], 0, 0, 0);
            }
            __builtin_amdgcn_s_setprio(0);

            // ---- softmax: p = exp2(s + alibi); packed bf16 store ----
            const bool diag = (ktg == qt);
            #pragma unroll
            for (int t = 0; t < 4; ++t) {
                float pv[4];
                #pragma unroll
                for (int r = 0; r < 4; ++r) {
                    const float x = (sacc[t][r] + alb[t]) + crk[r];
                    float e;
                    asm("v_exp_f32 %0, %1" : "=v"(e) : "v"(x));
                    if (diag && (koff[t] + r) > 0) e = 0.0f;
                    pv[r] = e;
                }
                l_one += (pv[0] + pv[1]) + (pv[2] + pv[3]);
                unsigned int lo, hi;
                asm("v_cvt_pk_bf16_f32 %0, %1, %2" : "=v"(lo) : "v"(pv[0]), "v"(pv[1]));
                asm("v_cvt_pk_bf16_f32 %0, %1, %2" : "=v"(hi) : "v"(pv[2]), "v"(pv[3]));
                uint2 w; w.x = lo; w.y = hi;
                *reinterpret_cast<uint2*>(&Pw[lm * PST + t * 16 + quad * 4]) = w;
            }
            #pragma unroll
            for (int r = 0; r < 4; ++r) crk[r] += d128;

            // ---- O += P V  (A=P from Ps[q][k], B=V^T) ----
            const short8 ap0 = *reinterpret_cast<const short8*>(&Pw[lm * PST + quad * 8]);
            const short8 ap1 = *reinterpret_cast<const short8*>(&Pw[lm * PST + 32 + quad * 8]);
            __builtin_amdgcn_s_setprio(1);
            #pragma unroll
            for (int t = 0; t < 4; ++t) {
                const short8 v0 = *reinterpret_cast<const short8*>(&Vs[grp][(t * 16 + lm) * KST + quad * 8]);
                const short8 v1 = *reinterpret_cast<const short8*>(&Vs[grp][(t * 16 + lm) * KST + 32 + quad * 8]);
                acc_o[t] = __builtin_amdgcn_mfma_f32_16x16x32_bf16(ap0, v0, acc_o[t], 0, 0, 0);
                acc_o[t] = __builtin_amdgcn_mfma_f32_16x16x32_bf16(ap1, v1, acc_o[t], 0, 0, 0);
            }
            __builtin_amdgcn_s_setprio(0);
        }
        __syncthreads();                 // all reads of pair i done

        if (i + 1 < niter) {
            // ---- write pair i+1 (in regs) to LDS; load pair i+2 ----
            *reinterpret_cast<short8*>(&Ks[0][srow * KST + sc8 * 8]) = ke;
            *reinterpret_cast<short8*>(&Ks[1][srow * KST + sc8 * 8]) = ko;
            *reinterpret_cast<short8*>(&Vs[0][srow * KST + sc8 * 8]) = ve;
            *reinterpret_cast<short8*>(&Vs[1][srow * KST + sc8 * 8]) = vo;
            if (i + 2 < niter) {
                const int e = (i + 2) * 2;
                ke = *reinterpret_cast<const short8*>(Kg + (size_t)(e * 64 + srow) * DH_ + sc8 * 8);
                ko = *reinterpret_cast<const short8*>(Kg + (size_t)((e + 1) * 64 + srow) * DH_ + sc8 * 8);
                ve = *reinterpret_cast<const short8*>(VTg + (size_t)srow * S_ + e * 64 + sc8 * 8);
                vo = *reinterpret_cast<const short8*>(VTg + (size_t)srow * S_ + (e + 1) * 64 + sc8 * 8);
            }
            __syncthreads();             // pair i+1 visible
        }
    }

    // ---- parity merge: odd group writes partials, even group reduces ----
    float* mb = reinterpret_cast<float*>(&Ps[0][0]);   // 4*64*17*4B = 17408B = Ps
    if (grp == 1) {
        const int idx = ((wave - 4) * 64 + lane) * 17;
        #pragma unroll
        for (int t = 0; t < 4; ++t)
            #pragma unroll
            for (int r = 0; r < 4; ++r)
                mb[idx + t * 4 + r] = acc_o[t][r];
        mb[idx + 16] = l_one;
    }
    __syncthreads();
    if (grp == 0) {
        const int idx = (wave * 64 + lane) * 17;
        #pragma unroll
        for (int t = 0; t < 4; ++t)
            #pragma unroll
            for (int r = 0; r < 4; ++r)
                acc_o[t][r] += mb[idx + t * 4 + r];
        l_one += mb[idx + 16];

        // l over k lives across quads -> xor 16,32; O /= l; store
        l_one += __shfl_xor(l_one, 16);
        l_one += __shfl_xor(l_one, 32);
        #pragma unroll
        for (int r = 0; r < 4; ++r) {
            const float lr = __shfl(l_one, quad * 4 + r);   // l for q-row quad*4+r
            const float inv_l = 1.0f / lr;
            const int s = qt * 64 + wq * 16 + quad * 4 + r;
            const size_t obase = ((size_t)(b * S_ + s) * H_ + h) * DH_;
            #pragma unroll
            for (int t = 0; t < 4; ++t)
                Ao[obase + t * 16 + lm] = f2bf(acc_o[t][r] * inv_l);
        }
    }
}

// ---------------------------------------------------------------------------
extern "C" void kernel_launch(void* const* d_in, const int* in_sizes, int n_in,
                              void* d_out, int out_size, void* d_ws, size_t ws_size,
                              hipStream_t stream)
{
    const float *x = nullptr, *w_qkv = nullptr, *b_qkv = nullptr,
                *w_out = nullptr, *b_out = nullptr;
    for (int i = 0; i < n_in; ++i) {
        switch (in_sizes[i]) {
            case 4194304: x     = (const float*)d_in[i]; break;
            case 3145728: w_qkv = (const float*)d_in[i]; break;
            case 3072:    b_qkv = (const float*)d_in[i]; break;
            case 1048576: w_out = (const float*)d_in[i]; break;
            case 1024:    b_out = (const float*)d_in[i]; break;
        }
    }
    if (!x)     x     = (const float*)d_in[0];
    if (!w_qkv) w_qkv = (const float*)d_in[1];
    if (!b_qkv) b_qkv = (const float*)d_in[2];
    if (!w_out) w_out = (const float*)d_in[3];
    if (!b_out) b_out = (const float*)d_in[4];

    float* out = (float*)d_out;                      // fp32 output
    unsigned short* ws16 = (unsigned short*)d_ws;

    // ws (ushort units): xb | wqkvT | woutT | Qb | Kb | Vb(V^T) | Aob = 48 MiB
    unsigned short* xb     = ws16;
    unsigned short* wqkvT  = ws16 + (size_t)4194304;
    unsigned short* woutT  = ws16 + (size_t)7340032;
    unsigned short* Qb     = ws16 + (size_t)8388608;
    unsigned short* Kb     = ws16 + (size_t)12582912;
    unsigned short* Vb     = ws16 + (size_t)16777216;
    unsigned short* Aob    = ws16 + (size_t)20971520;

    // merged prep: cvt_x + both weight transposes (one launch)
    prep<<<8192, 256, 0, stream>>>(x, xb, w_qkv, wqkvT, w_out, woutT);

    // QKV projection (MFMA) + bias + RoPE -> Q/K bf16 (B,H,S,DH), V^T (B,H,DH,S)
    gemm_qkv<<<dim3(24, 32), 256, 0, stream>>>(
        xb, wqkvT, b_qkv, Qb, Kb, Vb);
    // causal flash attention (MFMA v10, parity k-split) + ALiBi -> Aob bf16
    flash_mfma<<<dim3(1024), 512, 0, stream>>>(Qb, Kb, Vb, Aob);
    // output projection (MFMA, BM=64 / 512 blocks) + bias -> fp32 (B,S,DM)
    gemm_out<<<dim3(8, 64), 256, 0, stream>>>(Aob, woutT, b_out, out);
}

// Round 9
// 185.292 us; speedup vs baseline: 1.1262x; 1.1262x over previous
//
#include <hip/hip_runtime.h>
#include <math.h>

static constexpr int B_  = 2;
static constexpr int S_  = 2048;
static constexpr int H_  = 16;
static constexpr int DH_ = 64;
// Q pre-scale = 1/sqrt(192) * log2(e) so flash softmax uses raw v_exp_f32 (exp2)
static constexpr float QSCALE2_ = 0.104117589f;
static constexpr float C8L2_    = 11.5415603f;     // 8 * log2(e) (static-max shift)

typedef __attribute__((ext_vector_type(8))) short short8;   // 8 x bf16
typedef __attribute__((ext_vector_type(4))) float floatx4;  // MFMA acc

__device__ __forceinline__ float bf2f(unsigned short u) {
    union { unsigned int i; float f; } c; c.i = ((unsigned int)u) << 16; return c.f;
}
__device__ __forceinline__ unsigned short f2bf(float f) {
    union { float f; unsigned int i; } c; c.f = f;
    unsigned int x = c.i;
    unsigned int r = (x + 0x7fffu + ((x >> 16) & 1u)) >> 16;
    if ((x & 0x7f800000u) == 0x7f800000u) r = x >> 16;   // inf/nan passthrough
    return (unsigned short)r;
}
__device__ __forceinline__ void load_lds16(const unsigned short* g, unsigned short* l) {
    __builtin_amdgcn_global_load_lds(
        (const __attribute__((address_space(1))) unsigned int*)g,
        (__attribute__((address_space(3))) unsigned int*)l, 16, 0, 0);
}

// ---------------------------------------------------------------------------
// prep: one launch doing cvt_x (blocks 0..4095), w_qkv transpose
// (4096..7167), w_out transpose (7168..8191).
// ---------------------------------------------------------------------------
__global__ __launch_bounds__(256) void prep(
    const float* __restrict__ x,     unsigned short* __restrict__ xb,
    const float* __restrict__ w_qkv, unsigned short* __restrict__ wqkvT,
    const float* __restrict__ w_out, unsigned short* __restrict__ woutT)
{
    __shared__ float t[32][33];
    const int bid = blockIdx.x;
    if (bid < 4096) {
        const int i = bid * 256 + threadIdx.x;
        const float4 v = reinterpret_cast<const float4*>(x)[i];
        ushort4 r;
        r.x = f2bf(v.x); r.y = f2bf(v.y); r.z = f2bf(v.z); r.w = f2bf(v.w);
        reinterpret_cast<ushort4*>(xb)[i] = r;
        return;
    }
    const float* in; unsigned short* out; int NN, bx, by;
    if (bid < 7168) {
        in = w_qkv; out = wqkvT; NN = 3072;
        const int b2 = bid - 4096; bx = b2 % 96; by = b2 / 96;
    } else {
        in = w_out; out = woutT; NN = 1024;
        const int b2 = bid - 7168; bx = b2 & 31; by = b2 >> 5;
    }
    const int n0 = bx * 32;
    const int k0 = by * 32;
    const int tn = threadIdx.x & 31, tk = threadIdx.x >> 5;   // tk 0..7
    #pragma unroll
    for (int i = 0; i < 4; ++i)
        t[tk + 8 * i][tn] = in[(size_t)(k0 + tk + 8 * i) * NN + n0 + tn];
    __syncthreads();
    #pragma unroll
    for (int i = 0; i < 4; ++i)
        out[(size_t)(n0 + tk + 8 * i) * 1024 + k0 + tn] = f2bf(t[tn][tk + 8 * i]);
}

// ---------------------------------------------------------------------------
// MFMA GEMM: C(128x128) = A(Mx1024 bf16) * BT(3072x1024 bf16)^T.
// bias + RoPE epilogue:
//   Q -> bf16 (B,H,S,DH), scaled by 1/sqrt(192)*log2e
//   K -> bf16 (B,H,S,DH)
//   V -> bf16 (B,H,DH,S)  TRANSPOSED (so flash stages V^T with vector ops)
// ---------------------------------------------------------------------------
__global__ __launch_bounds__(256) void gemm_qkv(
    const unsigned short* __restrict__ A, const unsigned short* __restrict__ BT,
    const float* __restrict__ bias,
    unsigned short* __restrict__ O0, unsigned short* __restrict__ O1,
    unsigned short* __restrict__ O2)
{
    __shared__ unsigned short As[128 * 32];
    __shared__ unsigned short Bs[128 * 32];

    const int tid  = threadIdx.x;
    const int wave = tid >> 6;
    const int lane = tid & 63;
    const int quad = lane >> 4;
    const int lm   = lane & 15;
    const int wm = (wave >> 1) * 64;
    const int wn = (wave & 1) * 64;
    const int n0 = blockIdx.x * 128;
    const int m0 = blockIdx.y * 128;

    floatx4 acc[4][4] = {};

    const int sr = lane >> 2;
    const int sc = lane & 3;

    for (int k0 = 0; k0 < 1024; k0 += 32) {
        #pragma unroll
        for (int rep = 0; rep < 2; ++rep) {
            const int r = wave * 32 + rep * 16;
            load_lds16(A  + (size_t)(m0 + r + sr) * 1024 + k0 + sc * 8, &As[r * 32]);
            load_lds16(BT + (size_t)(n0 + r + sr) * 1024 + k0 + sc * 8, &Bs[r * 32]);
        }
        __syncthreads();
        short8 af[4], bf[4];
        #pragma unroll
        for (int i = 0; i < 4; ++i) {
            af[i] = *reinterpret_cast<const short8*>(&As[(wm + i * 16 + lm) * 32 + quad * 8]);
            bf[i] = *reinterpret_cast<const short8*>(&Bs[(wn + i * 16 + lm) * 32 + quad * 8]);
        }
        #pragma unroll
        for (int mi = 0; mi < 4; ++mi)
            #pragma unroll
            for (int ni = 0; ni < 4; ++ni)
                acc[mi][ni] = __builtin_amdgcn_mfma_f32_16x16x32_bf16(
                    af[mi], bf[ni], acc[mi][ni], 0, 0, 0);
        __syncthreads();
    }

    const int nbase = n0 + wn;
    const int h   = nbase / 192;
    const int sec = (nbase - h * 192) >> 6;      // 0=q 1=k 2=v
    float bia[4];
    #pragma unroll
    for (int ni = 0; ni < 4; ++ni) bia[ni] = bias[nbase + ni * 16 + lm];
    unsigned short* Out = (sec == 0) ? O0 : ((sec == 1) ? O1 : O2);

    if (sec == 2) {
        // V^T store: (B,H,DH,S); lane holds 4 consecutive s -> ushort4
        #pragma unroll
        for (int mi = 0; mi < 4; ++mi) {
            const int m  = m0 + wm + mi * 16 + quad * 4;
            const int bb = m >> 11;
            const int s  = m & (S_ - 1);
            const size_t rowb = (size_t)(bb * H_ + h) * DH_;
            #pragma unroll
            for (int ni = 0; ni < 4; ++ni) {
                const int d = ni * 16 + lm;
                ushort4 w;
                w.x = f2bf(acc[mi][ni][0] + bia[ni]);
                w.y = f2bf(acc[mi][ni][1] + bia[ni]);
                w.z = f2bf(acc[mi][ni][2] + bia[ni]);
                w.w = f2bf(acc[mi][ni][3] + bia[ni]);
                *reinterpret_cast<ushort4*>(&Out[(rowb + d) * S_ + s]) = w;
            }
        }
    } else {
        const float qscale = (sec == 0) ? QSCALE2_ : 1.0f;
        const float nlf = -13.287712379549449f / 32.0f;   // -log2(1e4)/32
        const float invf0 = exp2f((float)lm * nlf);
        const float invf1 = exp2f((float)(lm + 16) * nlf);
        #pragma unroll
        for (int mi = 0; mi < 4; ++mi) {
            #pragma unroll
            for (int r = 0; r < 4; ++r) {
                const int m  = m0 + wm + mi * 16 + quad * 4 + r;
                const int bb = m >> 11;
                const int s  = m & (S_ - 1);
                const size_t obase = ((size_t)(bb * H_ + h) * S_ + s) * DH_;
                const float a0 = (float)s * invf0, a1 = (float)s * invf1;
                const float sn0 = __sinf(a0), cs0 = __cosf(a0);
                const float sn1 = __sinf(a1), cs1 = __cosf(a1);
                #pragma unroll
                for (int ni = 0; ni < 4; ++ni) {
                    const int d = ni * 16 + lm;
                    const float v = acc[mi][ni][r]     + bia[ni];
                    const float p = acc[mi][ni ^ 2][r] + bia[ni ^ 2];  // d^32 partner
                    const float cs = (ni & 1) ? cs1 : cs0;
                    const float sn = (ni & 1) ? sn1 : sn0;
                    float res = (d < 32) ? (v * cs - p * sn) : (v * cs + p * sn);
                    Out[obase + d] = f2bf(res * qscale);
                }
            }
        }
    }
}

// ---------------------------------------------------------------------------
// Output projection: C(64x128) tiles = A(4096x1024 bf16) * BT(1024x1024)^T.
// BM=64 -> grid 8x64 = 512 blocks = 2 blocks/CU (cross-block barrier overlap).
// ---------------------------------------------------------------------------
__global__ __launch_bounds__(256) void gemm_out(
    const unsigned short* __restrict__ A, const unsigned short* __restrict__ BT,
    const float* __restrict__ bias, float* __restrict__ Of)
{
    __shared__ unsigned short As[64 * 32];
    __shared__ unsigned short Bs[128 * 32];

    const int tid  = threadIdx.x;
    const int wave = tid >> 6;
    const int lane = tid & 63;
    const int quad = lane >> 4;
    const int lm   = lane & 15;
    const int wm = (wave >> 1) * 32;
    const int wn = (wave & 1) * 64;
    const int n0 = blockIdx.x * 128;
    const int m0 = blockIdx.y * 64;

    floatx4 acc[2][4] = {};

    const int sr = lane >> 2;
    const int sc = lane & 3;

    for (int k0 = 0; k0 < 1024; k0 += 32) {
        load_lds16(A + (size_t)(m0 + wave * 16 + sr) * 1024 + k0 + sc * 8,
                   &As[wave * 16 * 32]);
        #pragma unroll
        for (int rep = 0; rep < 2; ++rep) {
            const int r = wave * 32 + rep * 16;
            load_lds16(BT + (size_t)(n0 + r + sr) * 1024 + k0 + sc * 8, &Bs[r * 32]);
        }
        __syncthreads();
        short8 af[2], bf[4];
        #pragma unroll
        for (int i = 0; i < 2; ++i)
            af[i] = *reinterpret_cast<const short8*>(&As[(wm + i * 16 + lm) * 32 + quad * 8]);
        #pragma unroll
        for (int i = 0; i < 4; ++i)
            bf[i] = *reinterpret_cast<const short8*>(&Bs[(wn + i * 16 + lm) * 32 + quad * 8]);
        #pragma unroll
        for (int mi = 0; mi < 2; ++mi)
            #pragma unroll
            for (int ni = 0; ni < 4; ++ni)
                acc[mi][ni] = __builtin_amdgcn_mfma_f32_16x16x32_bf16(
                    af[mi], bf[ni], acc[mi][ni], 0, 0, 0);
        __syncthreads();
    }

    #pragma unroll
    for (int ni = 0; ni < 4; ++ni) {
        const int gn = n0 + wn + ni * 16 + lm;
        const float b = bias[gn];
        #pragma unroll
        for (int mi = 0; mi < 2; ++mi) {
            const int gm = m0 + wm + mi * 16 + quad * 4;
            #pragma unroll
            for (int r = 0; r < 4; ++r)
                Of[(size_t)(gm + r) * 1024 + gn] = acc[mi][ni][r] + b;
        }
    }
}

// ---------------------------------------------------------------------------
// MFMA flash attention v11: v10 parity k-split, SPILL-FREE.
//  - __launch_bounds__(512,4): VGPR cap 64 (v10's (512,6) cap ~42 forced
//    ~160B/thread scratch spill -> 90MB HBM write traffic, the R8 regression).
//  - TRANSIENT staging: pair i+1 staged global->reg->LDS after the read
//    barrier (regs dead immediately, not live across compute). Staging
//    latency is covered by cross-block TLP (3 blocks/CU via 52.2KB LDS).
//  - block = ONE 64-q tile, 8 waves = 4 q-strips x 2 kt-parities; all waves
//    active every iter; end-of-block parity merge via Ps buffer.
//  - swapped QK^T, exp2 softmax, cvt_pk P-store, conflict-free staging.
// ---------------------------------------------------------------------------
static constexpr int KST = 68;   // Ks/Vs row stride (ushorts)
static constexpr int PST = 68;   // Ps row stride

__global__ __launch_bounds__(512, 4) void flash_mfma(
    const unsigned short* __restrict__ Q, const unsigned short* __restrict__ K,
    const unsigned short* __restrict__ VT, unsigned short* __restrict__ Ao)
{
    __shared__ unsigned short Ks[2][64 * KST];     // [parity][key][d]
    __shared__ unsigned short Vs[2][64 * KST];     // [parity][d][key]
    __shared__ unsigned short Ps[8][16 * PST];     // per-wave P / merge buffer

    const int bid = blockIdx.x;          // 0..1023
    const int qt  = 31 - (bid >> 5);     // heavy q-tiles first
    const int bh  = bid & 31;
    const int h   = bh & 15;
    const int b   = bh >> 4;
    const int tid  = threadIdx.x;        // 0..511
    const int wave = tid >> 6;           // 0..7
    const int lane = tid & 63;
    const int quad = lane >> 4;
    const int lm   = lane & 15;
    const int grp  = wave >> 2;          // kt parity (0=even, 1=odd)
    const int wq   = wave & 3;           // q-strip
    const int niter = (qt + 2) >> 1;     // ceil((qt+1)/2)
    const int srow = tid >> 3;           // staging row 0..63
    const int sc8  = tid & 7;            // staging chunk 0..7

    const unsigned short* Kg  = K  + (size_t)bh * S_ * DH_;
    const unsigned short* VTg = VT + (size_t)bh * DH_ * S_;

    // slope * MAX_BIAS * log2e
    const float slope2 = exp2f(-0.5f * (float)(h + 1)) * (8.0f * 1.44269504f);
    const float d64  = 64.0f * slope2;
    const float d128 = 2.0f * d64;

    int   koff[4];
    float alb[4];
    #pragma unroll
    for (int t = 0; t < 4; ++t) {
        koff[t] = t * 16 + quad * 4 - wq * 16 - lm;
        alb[t]  = (float)koff[t] * slope2 - C8L2_;
    }

    unsigned short* Pw = &Ps[wave][0];

    // Q B-frags: col q = lm of this wave's 16-q strip
    const unsigned short* Qrow =
        Q + ((size_t)bh * S_ + (size_t)(qt * 64 + wq * 16 + lm)) * DH_;
    const short8 aq0 = *reinterpret_cast<const short8*>(Qrow + quad * 8);
    const short8 aq1 = *reinterpret_cast<const short8*>(Qrow + 32 + quad * 8);

    float crk[4];
    #pragma unroll
    for (int r = 0; r < 4; ++r)
        crk[r] = (float)r * slope2 - (float)qt * d64 + (float)grp * d64;

    float l_one = 0.0f;
    floatx4 acc_o[4] = {};

    // ---- prologue: stage pair 0 (tiles 0,1) transiently ----
    {
        const short8 a = *reinterpret_cast<const short8*>(Kg + (size_t)srow * DH_ + sc8 * 8);
        const short8 c = *reinterpret_cast<const short8*>(Kg + (size_t)(64 + srow) * DH_ + sc8 * 8);
        const short8 e = *reinterpret_cast<const short8*>(VTg + (size_t)srow * S_ + sc8 * 8);
        const short8 g = *reinterpret_cast<const short8*>(VTg + (size_t)srow * S_ + 64 + sc8 * 8);
        *reinterpret_cast<short8*>(&Ks[0][srow * KST + sc8 * 8]) = a;
        *reinterpret_cast<short8*>(&Ks[1][srow * KST + sc8 * 8]) = c;
        *reinterpret_cast<short8*>(&Vs[0][srow * KST + sc8 * 8]) = e;
        *reinterpret_cast<short8*>(&Vs[1][srow * KST + sc8 * 8]) = g;
    }
    __syncthreads();

    for (int i = 0; i < niter; ++i) {
        const int ktg = 2 * i + grp;     // this wave-group's kt tile

        if (ktg <= qt) {
            // ---- S^T = K Q^T (swapped operands) ----
            floatx4 sacc[4] = {};
            __builtin_amdgcn_s_setprio(1);
            #pragma unroll
            for (int t = 0; t < 4; ++t) {
                const short8 k0 = *reinterpret_cast<const short8*>(&Ks[grp][(t * 16 + lm) * KST + quad * 8]);
                const short8 k1 = *reinterpret_cast<const short8*>(&Ks[grp][(t * 16 + lm) * KST + 32 + quad * 8]);
                sacc[t] = __builtin_amdgcn_mfma_f32_16x16x32_bf16(k0, aq0, sacc[t], 0, 0, 0);
                sacc[t] = __builtin_amdgcn_mfma_f32_16x16x32_bf16(k1, aq1, sacc[t], 0, 0, 0);
            }
            __builtin_amdgcn_s_setprio(0);

            // ---- softmax: p = exp2(s + alibi); packed bf16 store ----
            const bool diag = (ktg == qt);
            #pragma unroll
            for (int t = 0; t < 4; ++t) {
                float pv[4];
                #pragma unroll
                for (int r = 0; r < 4; ++r) {
                    const float x = (sacc[t][r] + alb[t]) + crk[r];
                    float e;
                    asm("v_exp_f32 %0, %1" : "=v"(e) : "v"(x));
                    if (diag && (koff[t] + r) > 0) e = 0.0f;
                    pv[r] = e;
                }
                l_one += (pv[0] + pv[1]) + (pv[2] + pv[3]);
                unsigned int lo, hi;
                asm("v_cvt_pk_bf16_f32 %0, %1, %2" : "=v"(lo) : "v"(pv[0]), "v"(pv[1]));
                asm("v_cvt_pk_bf16_f32 %0, %1, %2" : "=v"(hi) : "v"(pv[2]), "v"(pv[3]));
                uint2 w; w.x = lo; w.y = hi;
                *reinterpret_cast<uint2*>(&Pw[lm * PST + t * 16 + quad * 4]) = w;
            }
            #pragma unroll
            for (int r = 0; r < 4; ++r) crk[r] += d128;

            // ---- O += P V  (A=P from Ps[q][k], B=V^T) ----
            const short8 ap0 = *reinterpret_cast<const short8*>(&Pw[lm * PST + quad * 8]);
            const short8 ap1 = *reinterpret_cast<const short8*>(&Pw[lm * PST + 32 + quad * 8]);
            __builtin_amdgcn_s_setprio(1);
            #pragma unroll
            for (int t = 0; t < 4; ++t) {
                const short8 v0 = *reinterpret_cast<const short8*>(&Vs[grp][(t * 16 + lm) * KST + quad * 8]);
                const short8 v1 = *reinterpret_cast<const short8*>(&Vs[grp][(t * 16 + lm) * KST + 32 + quad * 8]);
                acc_o[t] = __builtin_amdgcn_mfma_f32_16x16x32_bf16(ap0, v0, acc_o[t], 0, 0, 0);
                acc_o[t] = __builtin_amdgcn_mfma_f32_16x16x32_bf16(ap1, v1, acc_o[t], 0, 0, 0);
            }
            __builtin_amdgcn_s_setprio(0);
        }
        __syncthreads();                 // all reads of pair i done

        if (i + 1 < niter) {
            // ---- stage pair i+1 transiently (regs not live across compute) ----
            const int e0 = (i + 1) * 128;
            const short8 a = *reinterpret_cast<const short8*>(Kg + (size_t)(e0 + srow) * DH_ + sc8 * 8);
            const short8 c = *reinterpret_cast<const short8*>(Kg + (size_t)(e0 + 64 + srow) * DH_ + sc8 * 8);
            const short8 e = *reinterpret_cast<const short8*>(VTg + (size_t)srow * S_ + e0 + sc8 * 8);
            const short8 g = *reinterpret_cast<const short8*>(VTg + (size_t)srow * S_ + e0 + 64 + sc8 * 8);
            *reinterpret_cast<short8*>(&Ks[0][srow * KST + sc8 * 8]) = a;
            *reinterpret_cast<short8*>(&Ks[1][srow * KST + sc8 * 8]) = c;
            *reinterpret_cast<short8*>(&Vs[0][srow * KST + sc8 * 8]) = e;
            *reinterpret_cast<short8*>(&Vs[1][srow * KST + sc8 * 8]) = g;
            __syncthreads();             // pair i+1 visible
        }
    }

    // ---- parity merge: odd group writes partials, even group reduces ----
    float* mb = reinterpret_cast<float*>(&Ps[0][0]);   // 4*64*17*4B = 17408B = Ps
    if (grp == 1) {
        const int idx = ((wave - 4) * 64 + lane) * 17;
        #pragma unroll
        for (int t = 0; t < 4; ++t)
            #pragma unroll
            for (int r = 0; r < 4; ++r)
                mb[idx + t * 4 + r] = acc_o[t][r];
        mb[idx + 16] = l_one;
    }
    __syncthreads();
    if (grp == 0) {
        const int idx = (wave * 64 + lane) * 17;
        #pragma unroll
        for (int t = 0; t < 4; ++t)
            #pragma unroll
            for (int r = 0; r < 4; ++r)
                acc_o[t][r] += mb[idx + t * 4 + r];
        l_one += mb[idx + 16];

        // l over k lives across quads -> xor 16,32; O /= l; store
        l_one += __shfl_xor(l_one, 16);
        l_one += __shfl_xor(l_one, 32);
        #pragma unroll
        for (int r = 0; r < 4; ++r) {
            const float lr = __shfl(l_one, quad * 4 + r);   // l for q-row quad*4+r
            const float inv_l = 1.0f / lr;
            const int s = qt * 64 + wq * 16 + quad * 4 + r;
            const size_t obase = ((size_t)(b * S_ + s) * H_ + h) * DH_;
            #pragma unroll
            for (int t = 0; t < 4; ++t)
                Ao[obase + t * 16 + lm] = f2bf(acc_o[t][r] * inv_l);
        }
    }
}

// ---------------------------------------------------------------------------
extern "C" void kernel_launch(void* const* d_in, const int* in_sizes, int n_in,
                              void* d_out, int out_size, void* d_ws, size_t ws_size,
                              hipStream_t stream)
{
    const float *x = nullptr, *w_qkv = nullptr, *b_qkv = nullptr,
                *w_out = nullptr, *b_out = nullptr;
    for (int i = 0; i < n_in; ++i) {
        switch (in_sizes[i]) {
            case 4194304: x     = (const float*)d_in[i]; break;
            case 3145728: w_qkv = (const float*)d_in[i]; break;
            case 3072:    b_qkv = (const float*)d_in[i]; break;
            case 1048576: w_out = (const float*)d_in[i]; break;
            case 1024:    b_out = (const float*)d_in[i]; break;
        }
    }
    if (!x)     x     = (const float*)d_in[0];
    if (!w_qkv) w_qkv = (const float*)d_in[1];
    if (!b_qkv) b_qkv = (const float*)d_in[2];
    if (!w_out) w_out = (const float*)d_in[3];
    if (!b_out) b_out = (const float*)d_in[4];

    float* out = (float*)d_out;                      // fp32 output
    unsigned short* ws16 = (unsigned short*)d_ws;

    // ws (ushort units): xb | wqkvT | woutT | Qb | Kb | Vb(V^T) | Aob = 48 MiB
    unsigned short* xb     = ws16;
    unsigned short* wqkvT  = ws16 + (size_t)4194304;
    unsigned short* woutT  = ws16 + (size_t)7340032;
    unsigned short* Qb     = ws16 + (size_t)8388608;
    unsigned short* Kb     = ws16 + (size_t)12582912;
    unsigned short* Vb     = ws16 + (size_t)16777216;
    unsigned short* Aob    = ws16 + (size_t)20971520;

    // merged prep: cvt_x + both weight transposes (one launch)
    prep<<<8192, 256, 0, stream>>>(x, xb, w_qkv, wqkvT, w_out, woutT);

    // QKV projection (MFMA) + bias + RoPE -> Q/K bf16 (B,H,S,DH), V^T (B,H,DH,S)
    gemm_qkv<<<dim3(24, 32), 256, 0, stream>>>(
        xb, wqkvT, b_qkv, Qb, Kb, Vb);
    // causal flash attention (MFMA v11, spill-free parity k-split) -> Aob bf16
    flash_mfma<<<dim3(1024), 512, 0, stream>>>(Qb, Kb, Vb, Aob);
    // output projection (MFMA, BM=64 / 512 blocks) + bias -> fp32 (B,S,DM)
    gemm_out<<<dim3(8, 64), 256, 0, stream>>>(Aob, woutT, b_out, out);
}

// Round 10
// 174.668 us; speedup vs baseline: 1.1947x; 1.0608x over previous
//
#include <hip/hip_runtime.h>
#include <math.h>

static constexpr int B_  = 2;
static constexpr int S_  = 2048;
static constexpr int H_  = 16;
static constexpr int DH_ = 64;
// Q pre-scale = 1/sqrt(192) * log2(e) so flash softmax uses raw v_exp_f32 (exp2)
static constexpr float QSCALE2_ = 0.104117589f;
static constexpr float C8L2_    = 11.5415603f;     // 8 * log2(e) (static-max shift)

typedef __attribute__((ext_vector_type(8))) short short8;   // 8 x bf16
typedef __attribute__((ext_vector_type(4))) float floatx4;  // MFMA acc

__device__ __forceinline__ float bf2f(unsigned short u) {
    union { unsigned int i; float f; } c; c.i = ((unsigned int)u) << 16; return c.f;
}
__device__ __forceinline__ unsigned short f2bf(float f) {
    union { float f; unsigned int i; } c; c.f = f;
    unsigned int x = c.i;
    unsigned int r = (x + 0x7fffu + ((x >> 16) & 1u)) >> 16;
    if ((x & 0x7f800000u) == 0x7f800000u) r = x >> 16;   // inf/nan passthrough
    return (unsigned short)r;
}
__device__ __forceinline__ void load_lds16(const unsigned short* g, unsigned short* l) {
    __builtin_amdgcn_global_load_lds(
        (const __attribute__((address_space(1))) unsigned int*)g,
        (__attribute__((address_space(3))) unsigned int*)l, 16, 0, 0);
}

// ---------------------------------------------------------------------------
// prep: one launch doing cvt_x (blocks 0..4095), w_qkv transpose
// (4096..7167), w_out transpose (7168..8191).
// ---------------------------------------------------------------------------
__global__ __launch_bounds__(256) void prep(
    const float* __restrict__ x,     unsigned short* __restrict__ xb,
    const float* __restrict__ w_qkv, unsigned short* __restrict__ wqkvT,
    const float* __restrict__ w_out, unsigned short* __restrict__ woutT)
{
    __shared__ float t[32][33];
    const int bid = blockIdx.x;
    if (bid < 4096) {
        const int i = bid * 256 + threadIdx.x;
        const float4 v = reinterpret_cast<const float4*>(x)[i];
        ushort4 r;
        r.x = f2bf(v.x); r.y = f2bf(v.y); r.z = f2bf(v.z); r.w = f2bf(v.w);
        reinterpret_cast<ushort4*>(xb)[i] = r;
        return;
    }
    const float* in; unsigned short* out; int NN, bx, by;
    if (bid < 7168) {
        in = w_qkv; out = wqkvT; NN = 3072;
        const int b2 = bid - 4096; bx = b2 % 96; by = b2 / 96;
    } else {
        in = w_out; out = woutT; NN = 1024;
        const int b2 = bid - 7168; bx = b2 & 31; by = b2 >> 5;
    }
    const int n0 = bx * 32;
    const int k0 = by * 32;
    const int tn = threadIdx.x & 31, tk = threadIdx.x >> 5;   // tk 0..7
    #pragma unroll
    for (int i = 0; i < 4; ++i)
        t[tk + 8 * i][tn] = in[(size_t)(k0 + tk + 8 * i) * NN + n0 + tn];
    __syncthreads();
    #pragma unroll
    for (int i = 0; i < 4; ++i)
        out[(size_t)(n0 + tk + 8 * i) * 1024 + k0 + tn] = f2bf(t[tn][tk + 8 * i]);
}

// ---------------------------------------------------------------------------
// MFMA GEMM: C(128x128) = A(Mx1024 bf16) * BT(3072x1024 bf16)^T.
// bias + RoPE epilogue:
//   Q -> bf16 (B,H,S,DH), scaled by 1/sqrt(192)*log2e
//   K -> bf16 (B,H,S,DH)
//   V -> bf16 (B,H,DH,S)  TRANSPOSED (so flash stages V^T with vector ops)
// ---------------------------------------------------------------------------
__global__ __launch_bounds__(256) void gemm_qkv(
    const unsigned short* __restrict__ A, const unsigned short* __restrict__ BT,
    const float* __restrict__ bias,
    unsigned short* __restrict__ O0, unsigned short* __restrict__ O1,
    unsigned short* __restrict__ O2)
{
    __shared__ unsigned short As[128 * 32];
    __shared__ unsigned short Bs[128 * 32];

    const int tid  = threadIdx.x;
    const int wave = tid >> 6;
    const int lane = tid & 63;
    const int quad = lane >> 4;
    const int lm   = lane & 15;
    const int wm = (wave >> 1) * 64;
    const int wn = (wave & 1) * 64;
    const int n0 = blockIdx.x * 128;
    const int m0 = blockIdx.y * 128;

    floatx4 acc[4][4] = {};

    const int sr = lane >> 2;
    const int sc = lane & 3;

    for (int k0 = 0; k0 < 1024; k0 += 32) {
        #pragma unroll
        for (int rep = 0; rep < 2; ++rep) {
            const int r = wave * 32 + rep * 16;
            load_lds16(A  + (size_t)(m0 + r + sr) * 1024 + k0 + sc * 8, &As[r * 32]);
            load_lds16(BT + (size_t)(n0 + r + sr) * 1024 + k0 + sc * 8, &Bs[r * 32]);
        }
        __syncthreads();
        short8 af[4], bf[4];
        #pragma unroll
        for (int i = 0; i < 4; ++i) {
            af[i] = *reinterpret_cast<const short8*>(&As[(wm + i * 16 + lm) * 32 + quad * 8]);
            bf[i] = *reinterpret_cast<const short8*>(&Bs[(wn + i * 16 + lm) * 32 + quad * 8]);
        }
        #pragma unroll
        for (int mi = 0; mi < 4; ++mi)
            #pragma unroll
            for (int ni = 0; ni < 4; ++ni)
                acc[mi][ni] = __builtin_amdgcn_mfma_f32_16x16x32_bf16(
                    af[mi], bf[ni], acc[mi][ni], 0, 0, 0);
        __syncthreads();
    }

    const int nbase = n0 + wn;
    const int h   = nbase / 192;
    const int sec = (nbase - h * 192) >> 6;      // 0=q 1=k 2=v
    float bia[4];
    #pragma unroll
    for (int ni = 0; ni < 4; ++ni) bia[ni] = bias[nbase + ni * 16 + lm];
    unsigned short* Out = (sec == 0) ? O0 : ((sec == 1) ? O1 : O2);

    if (sec == 2) {
        // V^T store: (B,H,DH,S); lane holds 4 consecutive s -> ushort4
        #pragma unroll
        for (int mi = 0; mi < 4; ++mi) {
            const int m  = m0 + wm + mi * 16 + quad * 4;
            const int bb = m >> 11;
            const int s  = m & (S_ - 1);
            const size_t rowb = (size_t)(bb * H_ + h) * DH_;
            #pragma unroll
            for (int ni = 0; ni < 4; ++ni) {
                const int d = ni * 16 + lm;
                ushort4 w;
                w.x = f2bf(acc[mi][ni][0] + bia[ni]);
                w.y = f2bf(acc[mi][ni][1] + bia[ni]);
                w.z = f2bf(acc[mi][ni][2] + bia[ni]);
                w.w = f2bf(acc[mi][ni][3] + bia[ni]);
                *reinterpret_cast<ushort4*>(&Out[(rowb + d) * S_ + s]) = w;
            }
        }
    } else {
        const float qscale = (sec == 0) ? QSCALE2_ : 1.0f;
        const float nlf = -13.287712379549449f / 32.0f;   // -log2(1e4)/32
        const float invf0 = exp2f((float)lm * nlf);
        const float invf1 = exp2f((float)(lm + 16) * nlf);
        #pragma unroll
        for (int mi = 0; mi < 4; ++mi) {
            #pragma unroll
            for (int r = 0; r < 4; ++r) {
                const int m  = m0 + wm + mi * 16 + quad * 4 + r;
                const int bb = m >> 11;
                const int s  = m & (S_ - 1);
                const size_t obase = ((size_t)(bb * H_ + h) * S_ + s) * DH_;
                const float a0 = (float)s * invf0, a1 = (float)s * invf1;
                const float sn0 = __sinf(a0), cs0 = __cosf(a0);
                const float sn1 = __sinf(a1), cs1 = __cosf(a1);
                #pragma unroll
                for (int ni = 0; ni < 4; ++ni) {
                    const int d = ni * 16 + lm;
                    const float v = acc[mi][ni][r]     + bia[ni];
                    const float p = acc[mi][ni ^ 2][r] + bia[ni ^ 2];  // d^32 partner
                    const float cs = (ni & 1) ? cs1 : cs0;
                    const float sn = (ni & 1) ? sn1 : sn0;
                    float res = (d < 32) ? (v * cs - p * sn) : (v * cs + p * sn);
                    Out[obase + d] = f2bf(res * qscale);
                }
            }
        }
    }
}

// ---------------------------------------------------------------------------
// Output projection: C(64x128) tiles = A(4096x1024 bf16) * BT(1024x1024)^T.
// BM=64 -> grid 8x64 = 512 blocks = 2 blocks/CU (cross-block barrier overlap).
// ---------------------------------------------------------------------------
__global__ __launch_bounds__(256) void gemm_out(
    const unsigned short* __restrict__ A, const unsigned short* __restrict__ BT,
    const float* __restrict__ bias, float* __restrict__ Of)
{
    __shared__ unsigned short As[64 * 32];
    __shared__ unsigned short Bs[128 * 32];

    const int tid  = threadIdx.x;
    const int wave = tid >> 6;
    const int lane = tid & 63;
    const int quad = lane >> 4;
    const int lm   = lane & 15;
    const int wm = (wave >> 1) * 32;
    const int wn = (wave & 1) * 64;
    const int n0 = blockIdx.x * 128;
    const int m0 = blockIdx.y * 64;

    floatx4 acc[2][4] = {};

    const int sr = lane >> 2;
    const int sc = lane & 3;

    for (int k0 = 0; k0 < 1024; k0 += 32) {
        load_lds16(A + (size_t)(m0 + wave * 16 + sr) * 1024 + k0 + sc * 8,
                   &As[wave * 16 * 32]);
        #pragma unroll
        for (int rep = 0; rep < 2; ++rep) {
            const int r = wave * 32 + rep * 16;
            load_lds16(BT + (size_t)(n0 + r + sr) * 1024 + k0 + sc * 8, &Bs[r * 32]);
        }
        __syncthreads();
        short8 af[2], bf[4];
        #pragma unroll
        for (int i = 0; i < 2; ++i)
            af[i] = *reinterpret_cast<const short8*>(&As[(wm + i * 16 + lm) * 32 + quad * 8]);
        #pragma unroll
        for (int i = 0; i < 4; ++i)
            bf[i] = *reinterpret_cast<const short8*>(&Bs[(wn + i * 16 + lm) * 32 + quad * 8]);
        #pragma unroll
        for (int mi = 0; mi < 2; ++mi)
            #pragma unroll
            for (int ni = 0; ni < 4; ++ni)
                acc[mi][ni] = __builtin_amdgcn_mfma_f32_16x16x32_bf16(
                    af[mi], bf[ni], acc[mi][ni], 0, 0, 0);
        __syncthreads();
    }

    #pragma unroll
    for (int ni = 0; ni < 4; ++ni) {
        const int gn = n0 + wn + ni * 16 + lm;
        const float b = bias[gn];
        #pragma unroll
        for (int mi = 0; mi < 2; ++mi) {
            const int gm = m0 + wm + mi * 16 + quad * 4;
            #pragma unroll
            for (int r = 0; r < 4; ++r)
                Of[(size_t)(gm + r) * 1024 + gn] = acc[mi][ni][r] + b;
        }
    }
}

// ---------------------------------------------------------------------------
// MFMA flash attention v12: v7 body (hidden staging) + XOR-swizzled 40KB LDS
// -> 4 blocks/CU, 16 ALL-ACTIVE waves/CU.
//  - one 64-q tile per block, 4 waves, K/V double-buffered, reg prefetch 2
//    tiles ahead, ONE barrier per iteration (all proven in v7 @ 58.4us with
//    only 2 blocks/CU; v9/v11 showed concurrency is the lever).
//  - KST 68 -> 64: pad replaced by chunk XOR-swizzle (chunk ^= row&7,
//    16B units, same involution on write and read; 16B-aligned, conflict-
//    neutral at b128 volume floor). LDS = 2x8K(K) + 2x8K(V) + 8K(P) = 40960B
//    exactly -> 4 workgroups/CU (163840B = 160KiB).
//  - grid 1024 single-tile blocks, heavy-qt first (backfill balances causal
//    imbalance); bid&31=bh keeps each head's K/V on one XCD L2.
// ---------------------------------------------------------------------------
__global__ __launch_bounds__(256, 4) void flash_mfma(
    const unsigned short* __restrict__ Q, const unsigned short* __restrict__ K,
    const unsigned short* __restrict__ VT, unsigned short* __restrict__ Ao)
{
    __shared__ unsigned short Ks[2][64 * 64];      // [buf][key][d] swizzled
    __shared__ unsigned short VTs[2][64 * 64];     // [buf][d][key] swizzled
    __shared__ unsigned short Ps[4][16 * 64];      // per-wave P [q][key] swizzled

    const int bi = blockIdx.x;       // 0..1023
    const int qt = 31 - (bi >> 5);   // heavy q-tiles first
    const int bh = bi & 31;
    const int h  = bh & 15;
    const int b  = bh >> 4;
    const int tid  = threadIdx.x;
    const int wave = tid >> 6;
    const int lane = tid & 63;
    const int quad = lane >> 4;
    const int lm   = lane & 15;
    const int srow = tid >> 2;       // staging row 0..63
    const int sc8  = tid & 3;        // staging chunk 0..3 (+4 second half)

    // swizzled chunk indices (involution: chunk ^ (row&7))
    const int swa = (sc8)     ^ (srow & 7);   // staging chunk a
    const int swb = (sc8 + 4) ^ (srow & 7);   // staging chunk b
    const int rq0 = (quad)     ^ (lm & 7);    // read chunk, first 32
    const int rq1 = (quad + 4) ^ (lm & 7);    // read chunk, second 32

    const unsigned short* Kg  = K  + (size_t)bh * S_ * DH_;
    const unsigned short* VTg = VT + (size_t)bh * DH_ * S_;

    // slope * MAX_BIAS * log2e
    const float slope2 = exp2f(-0.5f * (float)(h + 1)) * (8.0f * 1.44269504f);
    const float d64 = 64.0f * slope2;

    // per-t key offset relative to q: koff[t] = (t*16+quad*4) - (wave*16+lm)
    int   koff[4];
    float alb[4];
    #pragma unroll
    for (int t = 0; t < 4; ++t) {
        koff[t] = t * 16 + quad * 4 - wave * 16 - lm;
        alb[t]  = (float)koff[t] * slope2 - C8L2_;
    }

    unsigned short* Pw = &Ps[wave][0];
    // P-store swizzled offsets: logical ushort off in row lm = t*16 + quad*4
    // chunk = 2t + (quad>>1), sub = (quad&1)*4
    int pwr[4];
    #pragma unroll
    for (int t = 0; t < 4; ++t)
        pwr[t] = lm * 64 + ((2 * t + (quad >> 1)) ^ (lm & 7)) * 8 + (quad & 1) * 4;

    // Q B-frags: col q = lm of this wave's 16-q strip
    const unsigned short* Qrow =
        Q + ((size_t)bh * S_ + (size_t)(qt * 64 + wave * 16 + lm)) * DH_;
    const short8 aq0 = *reinterpret_cast<const short8*>(Qrow + quad * 8);
    const short8 aq1 = *reinterpret_cast<const short8*>(Qrow + 32 + quad * 8);

    float crk[4];
    #pragma unroll
    for (int r = 0; r < 4; ++r)
        crk[r] = (float)r * slope2 - (float)qt * d64;

    float l_one = 0.0f;
    floatx4 acc_o[4] = {};

    // ---- prologue: T0 -> regs -> buf0; T1 -> regs ----
    short8 ka, kb, va, vb;
    {
        const unsigned short* kr = Kg + (size_t)srow * DH_ + sc8 * 8;
        ka = *reinterpret_cast<const short8*>(kr);
        kb = *reinterpret_cast<const short8*>(kr + 32);
        const unsigned short* vr = VTg + (size_t)srow * S_ + sc8 * 8;
        va = *reinterpret_cast<const short8*>(vr);
        vb = *reinterpret_cast<const short8*>(vr + 32);
    }
    *reinterpret_cast<short8*>(&Ks[0][srow * 64 + swa * 8])  = ka;
    *reinterpret_cast<short8*>(&Ks[0][srow * 64 + swb * 8])  = kb;
    *reinterpret_cast<short8*>(&VTs[0][srow * 64 + swa * 8]) = va;
    *reinterpret_cast<short8*>(&VTs[0][srow * 64 + swb * 8]) = vb;
    if (qt > 0) {
        const unsigned short* kr = Kg + (size_t)(64 + srow) * DH_ + sc8 * 8;
        ka = *reinterpret_cast<const short8*>(kr);
        kb = *reinterpret_cast<const short8*>(kr + 32);
        const unsigned short* vr = VTg + (size_t)srow * S_ + 64 + sc8 * 8;
        va = *reinterpret_cast<const short8*>(vr);
        vb = *reinterpret_cast<const short8*>(vr + 32);
    }
    __syncthreads();

    for (int kt = 0; kt <= qt; ++kt) {
        const int cur = kt & 1;

        // ---- write tile kt+1 (in regs) to buf^1; issue loads for kt+2 ----
        if (kt < qt) {
            const int nxt = cur ^ 1;
            *reinterpret_cast<short8*>(&Ks[nxt][srow * 64 + swa * 8])  = ka;
            *reinterpret_cast<short8*>(&Ks[nxt][srow * 64 + swb * 8])  = kb;
            *reinterpret_cast<short8*>(&VTs[nxt][srow * 64 + swa * 8]) = va;
            *reinterpret_cast<short8*>(&VTs[nxt][srow * 64 + swb * 8]) = vb;
            if (kt + 1 < qt) {
                const unsigned short* kr =
                    Kg + (size_t)((kt + 2) * 64 + srow) * DH_ + sc8 * 8;
                ka = *reinterpret_cast<const short8*>(kr);
                kb = *reinterpret_cast<const short8*>(kr + 32);
                const unsigned short* vr =
                    VTg + (size_t)srow * S_ + (kt + 2) * 64 + sc8 * 8;
                va = *reinterpret_cast<const short8*>(vr);
                vb = *reinterpret_cast<const short8*>(vr + 32);
            }
        }

        // ---- S^T = K Q^T (swapped operands; swizzled reads) ----
        floatx4 sacc[4] = {};
        __builtin_amdgcn_s_setprio(1);
        #pragma unroll
        for (int t = 0; t < 4; ++t) {
            const short8 k0 = *reinterpret_cast<const short8*>(&Ks[cur][(t * 16 + lm) * 64 + rq0 * 8]);
            const short8 k1 = *reinterpret_cast<const short8*>(&Ks[cur][(t * 16 + lm) * 64 + rq1 * 8]);
            sacc[t] = __builtin_amdgcn_mfma_f32_16x16x32_bf16(k0, aq0, sacc[t], 0, 0, 0);
            sacc[t] = __builtin_amdgcn_mfma_f32_16x16x32_bf16(k1, aq1, sacc[t], 0, 0, 0);
        }
        __builtin_amdgcn_s_setprio(0);

        // ---- softmax: p = exp2(s + alibi); packed bf16 store (swizzled) ----
        const bool diag = (kt == qt);
        #pragma unroll
        for (int t = 0; t < 4; ++t) {
            float pv[4];
            #pragma unroll
            for (int r = 0; r < 4; ++r) {
                const float x = (sacc[t][r] + alb[t]) + crk[r];
                float e;
                asm("v_exp_f32 %0, %1" : "=v"(e) : "v"(x));
                if (diag && (koff[t] + r) > 0) e = 0.0f;
                pv[r] = e;
            }
            l_one += (pv[0] + pv[1]) + (pv[2] + pv[3]);
            unsigned int lo, hi;
            asm("v_cvt_pk_bf16_f32 %0, %1, %2" : "=v"(lo) : "v"(pv[0]), "v"(pv[1]));
            asm("v_cvt_pk_bf16_f32 %0, %1, %2" : "=v"(hi) : "v"(pv[2]), "v"(pv[3]));
            uint2 w; w.x = lo; w.y = hi;
            *reinterpret_cast<uint2*>(&Pw[pwr[t]]) = w;
        }
        #pragma unroll
        for (int r = 0; r < 4; ++r) crk[r] += d64;

        // ---- O += P V  (A=P from Ps[q][k] swizzled, B=V^T swizzled) ----
        const short8 ap0 = *reinterpret_cast<const short8*>(&Pw[lm * 64 + rq0 * 8]);
        const short8 ap1 = *reinterpret_cast<const short8*>(&Pw[lm * 64 + rq1 * 8]);
        __builtin_amdgcn_s_setprio(1);
        #pragma unroll
        for (int t = 0; t < 4; ++t) {
            const short8 v0 = *reinterpret_cast<const short8*>(&VTs[cur][(t * 16 + lm) * 64 + rq0 * 8]);
            const short8 v1 = *reinterpret_cast<const short8*>(&VTs[cur][(t * 16 + lm) * 64 + rq1 * 8]);
            acc_o[t] = __builtin_amdgcn_mfma_f32_16x16x32_bf16(ap0, v0, acc_o[t], 0, 0, 0);
            acc_o[t] = __builtin_amdgcn_mfma_f32_16x16x32_bf16(ap1, v1, acc_o[t], 0, 0, 0);
        }
        __builtin_amdgcn_s_setprio(0);
        __syncthreads();   // separates reads of buf[cur] from next iter's writes
    }

    // ---- epilogue: l over k lives across quads -> xor 16,32; O /= l ----
    l_one += __shfl_xor(l_one, 16);
    l_one += __shfl_xor(l_one, 32);
    #pragma unroll
    for (int r = 0; r < 4; ++r) {
        const float lr = __shfl(l_one, quad * 4 + r);   // l for q-row quad*4+r
        const float inv_l = 1.0f / lr;
        const int s = qt * 64 + wave * 16 + quad * 4 + r;
        const size_t obase = ((size_t)(b * S_ + s) * H_ + h) * DH_;
        #pragma unroll
        for (int t = 0; t < 4; ++t)
            Ao[obase + t * 16 + lm] = f2bf(acc_o[t][r] * inv_l);
    }
}

// ---------------------------------------------------------------------------
extern "C" void kernel_launch(void* const* d_in, const int* in_sizes, int n_in,
                              void* d_out, int out_size, void* d_ws, size_t ws_size,
                              hipStream_t stream)
{
    const float *x = nullptr, *w_qkv = nullptr, *b_qkv = nullptr,
                *w_out = nullptr, *b_out = nullptr;
    for (int i = 0; i < n_in; ++i) {
        switch (in_sizes[i]) {
            case 4194304: x     = (const float*)d_in[i]; break;
            case 3145728: w_qkv = (const float*)d_in[i]; break;
            case 3072:    b_qkv = (const float*)d_in[i]; break;
            case 1048576: w_out = (const float*)d_in[i]; break;
            case 1024:    b_out = (const float*)d_in[i]; break;
        }
    }
    if (!x)     x     = (const float*)d_in[0];
    if (!w_qkv) w_qkv = (const float*)d_in[1];
    if (!b_qkv) b_qkv = (const float*)d_in[2];
    if (!w_out) w_out = (const float*)d_in[3];
    if (!b_out) b_out = (const float*)d_in[4];

    float* out = (float*)d_out;                      // fp32 output
    unsigned short* ws16 = (unsigned short*)d_ws;

    // ws (ushort units): xb | wqkvT | woutT | Qb | Kb | Vb(V^T) | Aob = 48 MiB
    unsigned short* xb     = ws16;
    unsigned short* wqkvT  = ws16 + (size_t)4194304;
    unsigned short* woutT  = ws16 + (size_t)7340032;
    unsigned short* Qb     = ws16 + (size_t)8388608;
    unsigned short* Kb     = ws16 + (size_t)12582912;
    unsigned short* Vb     = ws16 + (size_t)16777216;
    unsigned short* Aob    = ws16 + (size_t)20971520;

    // merged prep: cvt_x + both weight transposes (one launch)
    prep<<<8192, 256, 0, stream>>>(x, xb, w_qkv, wqkvT, w_out, woutT);

    // QKV projection (MFMA) + bias + RoPE -> Q/K bf16 (B,H,S,DH), V^T (B,H,DH,S)
    gemm_qkv<<<dim3(24, 32), 256, 0, stream>>>(
        xb, wqkvT, b_qkv, Qb, Kb, Vb);
    // causal flash attention (MFMA v12, 4 blocks/CU swizzled) -> Aob bf16
    flash_mfma<<<dim3(1024), 256, 0, stream>>>(Qb, Kb, Vb, Aob);
    // output projection (MFMA, BM=64 / 512 blocks) + bias -> fp32 (B,S,DM)
    gemm_out<<<dim3(8, 64), 256, 0, stream>>>(Aob, woutT, b_out, out);
}

// Round 11
// 171.747 us; speedup vs baseline: 1.2150x; 1.0170x over previous
//
#include <hip/hip_runtime.h>
#include <math.h>

static constexpr int B_  = 2;
static constexpr int S_  = 2048;
static constexpr int H_  = 16;
static constexpr int DH_ = 64;
// Q pre-scale = 1/sqrt(192) * log2(e) so flash softmax uses raw v_exp_f32 (exp2)
static constexpr float QSCALE2_ = 0.104117589f;
static constexpr float C8L2_    = 11.5415603f;     // 8 * log2(e) (static-max shift)

typedef __attribute__((ext_vector_type(8))) short short8;   // 8 x bf16
typedef __attribute__((ext_vector_type(4))) float floatx4;  // MFMA acc

__device__ __forceinline__ float bf2f(unsigned short u) {
    union { unsigned int i; float f; } c; c.i = ((unsigned int)u) << 16; return c.f;
}
__device__ __forceinline__ unsigned short f2bf(float f) {
    union { float f; unsigned int i; } c; c.f = f;
    unsigned int x = c.i;
    unsigned int r = (x + 0x7fffu + ((x >> 16) & 1u)) >> 16;
    if ((x & 0x7f800000u) == 0x7f800000u) r = x >> 16;   // inf/nan passthrough
    return (unsigned short)r;
}
__device__ __forceinline__ void load_lds16(const unsigned short* g, unsigned short* l) {
    __builtin_amdgcn_global_load_lds(
        (const __attribute__((address_space(1))) unsigned int*)g,
        (__attribute__((address_space(3))) unsigned int*)l, 16, 0, 0);
}

// ---------------------------------------------------------------------------
// prep: one launch doing cvt_x (blocks 0..4095), w_qkv transpose
// (4096..7167), w_out transpose (7168..8191).
// ---------------------------------------------------------------------------
__global__ __launch_bounds__(256) void prep(
    const float* __restrict__ x,     unsigned short* __restrict__ xb,
    const float* __restrict__ w_qkv, unsigned short* __restrict__ wqkvT,
    const float* __restrict__ w_out, unsigned short* __restrict__ woutT)
{
    __shared__ float t[32][33];
    const int bid = blockIdx.x;
    if (bid < 4096) {
        const int i = bid * 256 + threadIdx.x;
        const float4 v = reinterpret_cast<const float4*>(x)[i];
        ushort4 r;
        r.x = f2bf(v.x); r.y = f2bf(v.y); r.z = f2bf(v.z); r.w = f2bf(v.w);
        reinterpret_cast<ushort4*>(xb)[i] = r;
        return;
    }
    const float* in; unsigned short* out; int NN, bx, by;
    if (bid < 7168) {
        in = w_qkv; out = wqkvT; NN = 3072;
        const int b2 = bid - 4096; bx = b2 % 96; by = b2 / 96;
    } else {
        in = w_out; out = woutT; NN = 1024;
        const int b2 = bid - 7168; bx = b2 & 31; by = b2 >> 5;
    }
    const int n0 = bx * 32;
    const int k0 = by * 32;
    const int tn = threadIdx.x & 31, tk = threadIdx.x >> 5;   // tk 0..7
    #pragma unroll
    for (int i = 0; i < 4; ++i)
        t[tk + 8 * i][tn] = in[(size_t)(k0 + tk + 8 * i) * NN + n0 + tn];
    __syncthreads();
    #pragma unroll
    for (int i = 0; i < 4; ++i)
        out[(size_t)(n0 + tk + 8 * i) * 1024 + k0 + tn] = f2bf(t[tn][tk + 8 * i]);
}

// ---------------------------------------------------------------------------
// MFMA GEMM: C(128x128) = A(Mx1024 bf16) * BT(3072x1024 bf16)^T.
// v13: BK=64 (half the barrier-drains of BK=32) + XOR chunk-swizzle
// (chunk ^= row&7, 16B units) staged via PRE-SWIZZLED GLOBAL SOURCE with
// linear global_load_lds dest, read back with the same involution ->
// 8-way LDS read conflict becomes 2-way (free). Accumulation order is
// bitwise identical to BK=32 (same K-slice sequence).
// bias + RoPE epilogue:
//   Q -> bf16 (B,H,S,DH), scaled by 1/sqrt(192)*log2e
//   K -> bf16 (B,H,S,DH)
//   V -> bf16 (B,H,DH,S)  TRANSPOSED
// ---------------------------------------------------------------------------
__global__ __launch_bounds__(256) void gemm_qkv(
    const unsigned short* __restrict__ A, const unsigned short* __restrict__ BT,
    const float* __restrict__ bias,
    unsigned short* __restrict__ O0, unsigned short* __restrict__ O1,
    unsigned short* __restrict__ O2)
{
    __shared__ unsigned short As[128 * 64];
    __shared__ unsigned short Bs[128 * 64];

    const int tid  = threadIdx.x;
    const int wave = tid >> 6;
    const int lane = tid & 63;
    const int quad = lane >> 4;
    const int lm   = lane & 15;
    const int wm = (wave >> 1) * 64;
    const int wn = (wave & 1) * 64;
    const int n0 = blockIdx.x * 128;
    const int m0 = blockIdx.y * 128;

    floatx4 acc[4][4] = {};

    const int sr8 = lane >> 3;       // staging row-within-8 (0..7)
    const int sc8 = lane & 7;        // staging chunk (0..7, 16B each)
    const int l7  = lm & 7;          // read-side row&7

    for (int k0 = 0; k0 < 1024; k0 += 64) {
        #pragma unroll
        for (int rep = 0; rep < 4; ++rep) {
            const int rr   = wave * 32 + rep * 8;      // wave-uniform base row
            const int srow = rr + sr8;                 // this lane's row
            const int gcol = (sc8 ^ (srow & 7)) * 8;   // pre-swizzled source col
            load_lds16(A  + (size_t)(m0 + srow) * 1024 + k0 + gcol, &As[rr * 64]);
            load_lds16(BT + (size_t)(n0 + srow) * 1024 + k0 + gcol, &Bs[rr * 64]);
        }
        __syncthreads();
        #pragma unroll
        for (int kk = 0; kk < 2; ++kk) {
            const int c = ((kk * 4 + quad) ^ l7) * 8;  // swizzled read chunk
            short8 af[4], bf[4];
            #pragma unroll
            for (int i = 0; i < 4; ++i) {
                af[i] = *reinterpret_cast<const short8*>(&As[(wm + i * 16 + lm) * 64 + c]);
                bf[i] = *reinterpret_cast<const short8*>(&Bs[(wn + i * 16 + lm) * 64 + c]);
            }
            #pragma unroll
            for (int mi = 0; mi < 4; ++mi)
                #pragma unroll
                for (int ni = 0; ni < 4; ++ni)
                    acc[mi][ni] = __builtin_amdgcn_mfma_f32_16x16x32_bf16(
                        af[mi], bf[ni], acc[mi][ni], 0, 0, 0);
        }
        __syncthreads();
    }

    const int nbase = n0 + wn;
    const int h   = nbase / 192;
    const int sec = (nbase - h * 192) >> 6;      // 0=q 1=k 2=v
    float bia[4];
    #pragma unroll
    for (int ni = 0; ni < 4; ++ni) bia[ni] = bias[nbase + ni * 16 + lm];
    unsigned short* Out = (sec == 0) ? O0 : ((sec == 1) ? O1 : O2);

    if (sec == 2) {
        // V^T store: (B,H,DH,S); lane holds 4 consecutive s -> ushort4
        #pragma unroll
        for (int mi = 0; mi < 4; ++mi) {
            const int m  = m0 + wm + mi * 16 + quad * 4;
            const int bb = m >> 11;
            const int s  = m & (S_ - 1);
            const size_t rowb = (size_t)(bb * H_ + h) * DH_;
            #pragma unroll
            for (int ni = 0; ni < 4; ++ni) {
                const int d = ni * 16 + lm;
                ushort4 w;
                w.x = f2bf(acc[mi][ni][0] + bia[ni]);
                w.y = f2bf(acc[mi][ni][1] + bia[ni]);
                w.z = f2bf(acc[mi][ni][2] + bia[ni]);
                w.w = f2bf(acc[mi][ni][3] + bia[ni]);
                *reinterpret_cast<ushort4*>(&Out[(rowb + d) * S_ + s]) = w;
            }
        }
    } else {
        const float qscale = (sec == 0) ? QSCALE2_ : 1.0f;
        const float nlf = -13.287712379549449f / 32.0f;   // -log2(1e4)/32
        const float invf0 = exp2f((float)lm * nlf);
        const float invf1 = exp2f((float)(lm + 16) * nlf);
        #pragma unroll
        for (int mi = 0; mi < 4; ++mi) {
            #pragma unroll
            for (int r = 0; r < 4; ++r) {
                const int m  = m0 + wm + mi * 16 + quad * 4 + r;
                const int bb = m >> 11;
                const int s  = m & (S_ - 1);
                const size_t obase = ((size_t)(bb * H_ + h) * S_ + s) * DH_;
                const float a0 = (float)s * invf0, a1 = (float)s * invf1;
                const float sn0 = __sinf(a0), cs0 = __cosf(a0);
                const float sn1 = __sinf(a1), cs1 = __cosf(a1);
                #pragma unroll
                for (int ni = 0; ni < 4; ++ni) {
                    const int d = ni * 16 + lm;
                    const float v = acc[mi][ni][r]     + bia[ni];
                    const float p = acc[mi][ni ^ 2][r] + bia[ni ^ 2];  // d^32 partner
                    const float cs = (ni & 1) ? cs1 : cs0;
                    const float sn = (ni & 1) ? sn1 : sn0;
                    float res = (d < 32) ? (v * cs - p * sn) : (v * cs + p * sn);
                    Out[obase + d] = f2bf(res * qscale);
                }
            }
        }
    }
}

// ---------------------------------------------------------------------------
// Output projection: C(64x128) tiles = A(4096x1024 bf16) * BT(1024x1024)^T.
// BM=64 -> grid 8x64 = 512 blocks = 2 blocks/CU (cross-block barrier overlap).
// ---------------------------------------------------------------------------
__global__ __launch_bounds__(256) void gemm_out(
    const unsigned short* __restrict__ A, const unsigned short* __restrict__ BT,
    const float* __restrict__ bias, float* __restrict__ Of)
{
    __shared__ unsigned short As[64 * 32];
    __shared__ unsigned short Bs[128 * 32];

    const int tid  = threadIdx.x;
    const int wave = tid >> 6;
    const int lane = tid & 63;
    const int quad = lane >> 4;
    const int lm   = lane & 15;
    const int wm = (wave >> 1) * 32;
    const int wn = (wave & 1) * 64;
    const int n0 = blockIdx.x * 128;
    const int m0 = blockIdx.y * 64;

    floatx4 acc[2][4] = {};

    const int sr = lane >> 2;
    const int sc = lane & 3;

    for (int k0 = 0; k0 < 1024; k0 += 32) {
        load_lds16(A + (size_t)(m0 + wave * 16 + sr) * 1024 + k0 + sc * 8,
                   &As[wave * 16 * 32]);
        #pragma unroll
        for (int rep = 0; rep < 2; ++rep) {
            const int r = wave * 32 + rep * 16;
            load_lds16(BT + (size_t)(n0 + r + sr) * 1024 + k0 + sc * 8, &Bs[r * 32]);
        }
        __syncthreads();
        short8 af[2], bf[4];
        #pragma unroll
        for (int i = 0; i < 2; ++i)
            af[i] = *reinterpret_cast<const short8*>(&As[(wm + i * 16 + lm) * 32 + quad * 8]);
        #pragma unroll
        for (int i = 0; i < 4; ++i)
            bf[i] = *reinterpret_cast<const short8*>(&Bs[(wn + i * 16 + lm) * 32 + quad * 8]);
        #pragma unroll
        for (int mi = 0; mi < 2; ++mi)
            #pragma unroll
            for (int ni = 0; ni < 4; ++ni)
                acc[mi][ni] = __builtin_amdgcn_mfma_f32_16x16x32_bf16(
                    af[mi], bf[ni], acc[mi][ni], 0, 0, 0);
        __syncthreads();
    }

    #pragma unroll
    for (int ni = 0; ni < 4; ++ni) {
        const int gn = n0 + wn + ni * 16 + lm;
        const float b = bias[gn];
        #pragma unroll
        for (int mi = 0; mi < 2; ++mi) {
            const int gm = m0 + wm + mi * 16 + quad * 4;
            #pragma unroll
            for (int r = 0; r < 4; ++r)
                Of[(size_t)(gm + r) * 1024 + gn] = acc[mi][ni][r] + b;
        }
    }
}

// ---------------------------------------------------------------------------
// MFMA flash attention v12: v7 body (hidden staging) + XOR-swizzled 40KB LDS
// -> 4 blocks/CU, 16 ALL-ACTIVE waves/CU.  (unchanged from R10)
// ---------------------------------------------------------------------------
__global__ __launch_bounds__(256, 4) void flash_mfma(
    const unsigned short* __restrict__ Q, const unsigned short* __restrict__ K,
    const unsigned short* __restrict__ VT, unsigned short* __restrict__ Ao)
{
    __shared__ unsigned short Ks[2][64 * 64];      // [buf][key][d] swizzled
    __shared__ unsigned short VTs[2][64 * 64];     // [buf][d][key] swizzled
    __shared__ unsigned short Ps[4][16 * 64];      // per-wave P [q][key] swizzled

    const int bi = blockIdx.x;       // 0..1023
    const int qt = 31 - (bi >> 5);   // heavy q-tiles first
    const int bh = bi & 31;
    const int h  = bh & 15;
    const int b  = bh >> 4;
    const int tid  = threadIdx.x;
    const int wave = tid >> 6;
    const int lane = tid & 63;
    const int quad = lane >> 4;
    const int lm   = lane & 15;
    const int srow = tid >> 2;       // staging row 0..63
    const int sc8  = tid & 3;        // staging chunk 0..3 (+4 second half)

    // swizzled chunk indices (involution: chunk ^ (row&7))
    const int swa = (sc8)     ^ (srow & 7);   // staging chunk a
    const int swb = (sc8 + 4) ^ (srow & 7);   // staging chunk b
    const int rq0 = (quad)     ^ (lm & 7);    // read chunk, first 32
    const int rq1 = (quad + 4) ^ (lm & 7);    // read chunk, second 32

    const unsigned short* Kg  = K  + (size_t)bh * S_ * DH_;
    const unsigned short* VTg = VT + (size_t)bh * DH_ * S_;

    // slope * MAX_BIAS * log2e
    const float slope2 = exp2f(-0.5f * (float)(h + 1)) * (8.0f * 1.44269504f);
    const float d64 = 64.0f * slope2;

    // per-t key offset relative to q: koff[t] = (t*16+quad*4) - (wave*16+lm)
    int   koff[4];
    float alb[4];
    #pragma unroll
    for (int t = 0; t < 4; ++t) {
        koff[t] = t * 16 + quad * 4 - wave * 16 - lm;
        alb[t]  = (float)koff[t] * slope2 - C8L2_;
    }

    unsigned short* Pw = &Ps[wave][0];
    // P-store swizzled offsets: logical ushort off in row lm = t*16 + quad*4
    // chunk = 2t + (quad>>1), sub = (quad&1)*4
    int pwr[4];
    #pragma unroll
    for (int t = 0; t < 4; ++t)
        pwr[t] = lm * 64 + ((2 * t + (quad >> 1)) ^ (lm & 7)) * 8 + (quad & 1) * 4;

    // Q B-frags: col q = lm of this wave's 16-q strip
    const unsigned short* Qrow =
        Q + ((size_t)bh * S_ + (size_t)(qt * 64 + wave * 16 + lm)) * DH_;
    const short8 aq0 = *reinterpret_cast<const short8*>(Qrow + quad * 8);
    const short8 aq1 = *reinterpret_cast<const short8*>(Qrow + 32 + quad * 8);

    float crk[4];
    #pragma unroll
    for (int r = 0; r < 4; ++r)
        crk[r] = (float)r * slope2 - (float)qt * d64;

    float l_one = 0.0f;
    floatx4 acc_o[4] = {};

    // ---- prologue: T0 -> regs -> buf0; T1 -> regs ----
    short8 ka, kb, va, vb;
    {
        const unsigned short* kr = Kg + (size_t)srow * DH_ + sc8 * 8;
        ka = *reinterpret_cast<const short8*>(kr);
        kb = *reinterpret_cast<const short8*>(kr + 32);
        const unsigned short* vr = VTg + (size_t)srow * S_ + sc8 * 8;
        va = *reinterpret_cast<const short8*>(vr);
        vb = *reinterpret_cast<const short8*>(vr + 32);
    }
    *reinterpret_cast<short8*>(&Ks[0][srow * 64 + swa * 8])  = ka;
    *reinterpret_cast<short8*>(&Ks[0][srow * 64 + swb * 8])  = kb;
    *reinterpret_cast<short8*>(&VTs[0][srow * 64 + swa * 8]) = va;
    *reinterpret_cast<short8*>(&VTs[0][srow * 64 + swb * 8]) = vb;
    if (qt > 0) {
        const unsigned short* kr = Kg + (size_t)(64 + srow) * DH_ + sc8 * 8;
        ka = *reinterpret_cast<const short8*>(kr);
        kb = *reinterpret_cast<const short8*>(kr + 32);
        const unsigned short* vr = VTg + (size_t)srow * S_ + 64 + sc8 * 8;
        va = *reinterpret_cast<const short8*>(vr);
        vb = *reinterpret_cast<const short8*>(vr + 32);
    }
    __syncthreads();

    for (int kt = 0; kt <= qt; ++kt) {
        const int cur = kt & 1;

        // ---- write tile kt+1 (in regs) to buf^1; issue loads for kt+2 ----
        if (kt < qt) {
            const int nxt = cur ^ 1;
            *reinterpret_cast<short8*>(&Ks[nxt][srow * 64 + swa * 8])  = ka;
            *reinterpret_cast<short8*>(&Ks[nxt][srow * 64 + swb * 8])  = kb;
            *reinterpret_cast<short8*>(&VTs[nxt][srow * 64 + swa * 8]) = va;
            *reinterpret_cast<short8*>(&VTs[nxt][srow * 64 + swb * 8]) = vb;
            if (kt + 1 < qt) {
                const unsigned short* kr =
                    Kg + (size_t)((kt + 2) * 64 + srow) * DH_ + sc8 * 8;
                ka = *reinterpret_cast<const short8*>(kr);
                kb = *reinterpret_cast<const short8*>(kr + 32);
                const unsigned short* vr =
                    VTg + (size_t)srow * S_ + (kt + 2) * 64 + sc8 * 8;
                va = *reinterpret_cast<const short8*>(vr);
                vb = *reinterpret_cast<const short8*>(vr + 32);
            }
        }

        // ---- S^T = K Q^T (swapped operands; swizzled reads) ----
        floatx4 sacc[4] = {};
        __builtin_amdgcn_s_setprio(1);
        #pragma unroll
        for (int t = 0; t < 4; ++t) {
            const short8 k0 = *reinterpret_cast<const short8*>(&Ks[cur][(t * 16 + lm) * 64 + rq0 * 8]);
            const short8 k1 = *reinterpret_cast<const short8*>(&Ks[cur][(t * 16 + lm) * 64 + rq1 * 8]);
            sacc[t] = __builtin_amdgcn_mfma_f32_16x16x32_bf16(k0, aq0, sacc[t], 0, 0, 0);
            sacc[t] = __builtin_amdgcn_mfma_f32_16x16x32_bf16(k1, aq1, sacc[t], 0, 0, 0);
        }
        __builtin_amdgcn_s_setprio(0);

        // ---- softmax: p = exp2(s + alibi); packed bf16 store (swizzled) ----
        const bool diag = (kt == qt);
        #pragma unroll
        for (int t = 0; t < 4; ++t) {
            float pv[4];
            #pragma unroll
            for (int r = 0; r < 4; ++r) {
                const float x = (sacc[t][r] + alb[t]) + crk[r];
                float e;
                asm("v_exp_f32 %0, %1" : "=v"(e) : "v"(x));
                if (diag && (koff[t] + r) > 0) e = 0.0f;
                pv[r] = e;
            }
            l_one += (pv[0] + pv[1]) + (pv[2] + pv[3]);
            unsigned int lo, hi;
            asm("v_cvt_pk_bf16_f32 %0, %1, %2" : "=v"(lo) : "v"(pv[0]), "v"(pv[1]));
            asm("v_cvt_pk_bf16_f32 %0, %1, %2" : "=v"(hi) : "v"(pv[2]), "v"(pv[3]));
            uint2 w; w.x = lo; w.y = hi;
            *reinterpret_cast<uint2*>(&Pw[pwr[t]]) = w;
        }
        #pragma unroll
        for (int r = 0; r < 4; ++r) crk[r] += d64;

        // ---- O += P V  (A=P from Ps[q][k] swizzled, B=V^T swizzled) ----
        const short8 ap0 = *reinterpret_cast<const short8*>(&Pw[lm * 64 + rq0 * 8]);
        const short8 ap1 = *reinterpret_cast<const short8*>(&Pw[lm * 64 + rq1 * 8]);
        __builtin_amdgcn_s_setprio(1);
        #pragma unroll
        for (int t = 0; t < 4; ++t) {
            const short8 v0 = *reinterpret_cast<const short8*>(&VTs[cur][(t * 16 + lm) * 64 + rq0 * 8]);
            const short8 v1 = *reinterpret_cast<const short8*>(&VTs[cur][(t * 16 + lm) * 64 + rq1 * 8]);
            acc_o[t] = __builtin_amdgcn_mfma_f32_16x16x32_bf16(ap0, v0, acc_o[t], 0, 0, 0);
            acc_o[t] = __builtin_amdgcn_mfma_f32_16x16x32_bf16(ap1, v1, acc_o[t], 0, 0, 0);
        }
        __builtin_amdgcn_s_setprio(0);
        __syncthreads();   // separates reads of buf[cur] from next iter's writes
    }

    // ---- epilogue: l over k lives across quads -> xor 16,32; O /= l ----
    l_one += __shfl_xor(l_one, 16);
    l_one += __shfl_xor(l_one, 32);
    #pragma unroll
    for (int r = 0; r < 4; ++r) {
        const float lr = __shfl(l_one, quad * 4 + r);   // l for q-row quad*4+r
        const float inv_l = 1.0f / lr;
        const int s = qt * 64 + wave * 16 + quad * 4 + r;
        const size_t obase = ((size_t)(b * S_ + s) * H_ + h) * DH_;
        #pragma unroll
        for (int t = 0; t < 4; ++t)
            Ao[obase + t * 16 + lm] = f2bf(acc_o[t][r] * inv_l);
    }
}

// ---------------------------------------------------------------------------
extern "C" void kernel_launch(void* const* d_in, const int* in_sizes, int n_in,
                              void* d_out, int out_size, void* d_ws, size_t ws_size,
                              hipStream_t stream)
{
    const float *x = nullptr, *w_qkv = nullptr, *b_qkv = nullptr,
                *w_out = nullptr, *b_out = nullptr;
    for (int i = 0; i < n_in; ++i) {
        switch (in_sizes[i]) {
            case 4194304: x     = (const float*)d_in[i]; break;
            case 3145728: w_qkv = (const float*)d_in[i]; break;
            case 3072:    b_qkv = (const float*)d_in[i]; break;
            case 1048576: w_out = (const float*)d_in[i]; break;
            case 1024:    b_out = (const float*)d_in[i]; break;
        }
    }
    if (!x)     x     = (const float*)d_in[0];
    if (!w_qkv) w_qkv = (const float*)d_in[1];
    if (!b_qkv) b_qkv = (const float*)d_in[2];
    if (!w_out) w_out = (const float*)d_in[3];
    if (!b_out) b_out = (const float*)d_in[4];

    float* out = (float*)d_out;                      // fp32 output
    unsigned short* ws16 = (unsigned short*)d_ws;

    // ws (ushort units): xb | wqkvT | woutT | Qb | Kb | Vb(V^T) | Aob = 48 MiB
    unsigned short* xb     = ws16;
    unsigned short* wqkvT  = ws16 + (size_t)4194304;
    unsigned short* woutT  = ws16 + (size_t)7340032;
    unsigned short* Qb     = ws16 + (size_t)8388608;
    unsigned short* Kb     = ws16 + (size_t)12582912;
    unsigned short* Vb     = ws16 + (size_t)16777216;
    unsigned short* Aob    = ws16 + (size_t)20971520;

    // merged prep: cvt_x + both weight transposes (one launch)
    prep<<<8192, 256, 0, stream>>>(x, xb, w_qkv, wqkvT, w_out, woutT);

    // QKV projection (MFMA, BK=64 swizzled) + bias + RoPE -> Q/K bf16, V^T
    gemm_qkv<<<dim3(24, 32), 256, 0, stream>>>(
        xb, wqkvT, b_qkv, Qb, Kb, Vb);
    // causal flash attention (MFMA v12, 4 blocks/CU swizzled) -> Aob bf16
    flash_mfma<<<dim3(1024), 256, 0, stream>>>(Qb, Kb, Vb, Aob);
    // output projection (MFMA, BM=64 / 512 blocks) + bias -> fp32 (B,S,DM)
    gemm_out<<<dim3(8, 64), 256, 0, stream>>>(Aob, woutT, b_out, out);
}